// Round 2
// baseline (105.421 us; speedup 1.0000x reference)
//
#include <hip/hip_runtime.h>

#define NH 8
#define LQ 384
#define LK 384
#define BS 2

typedef float v8f __attribute__((ext_vector_type(8)));
__device__ __forceinline__ v8f fma8(v8f a, v8f b, v8f c) { return __builtin_elementwise_fma(a, b, c); }
__device__ __forceinline__ v8f sp8(float x) { v8f r = {x, x, x, x, x, x, x, x}; return r; }

// ---------------- Kernel 1: Ek = exp(2*(kW+b1)), layout [bh][e4][k][4] ----------------
// grid = 384: bh = bid/24, 16-k tile. 1.5 blocks/CU.
__global__ __launch_bounds__(256) void pre_ek_kernel(
    const float* __restrict__ kin, const float* __restrict__ w1,
    const float* __restrict__ b1, float* __restrict__ ws)
{
    __shared__ float tile[16][65];
    const int bid = blockIdx.x;
    const int bh = bid / 24, kt = bid % 24;
    const int b = bh >> 3, h = bh & 7;
    const int k0 = kt * 16;
    const int tid = threadIdx.x;
    const int lane = tid & 63, w = tid >> 6;

    float w1c[32];
    const float* w1p = w1 + (size_t)(h * 64 + 32) * 64 + lane;
    #pragma unroll
    for (int d = 0; d < 32; ++d) w1c[d] = w1p[d * 64];
    const float bv = b1[h * 64 + lane];

    #pragma unroll
    for (int s = 0; s < 4; ++s) {
        int kr = w * 4 + s;
        const float* krow = kin + ((size_t)(b * LK + k0 + kr)) * (NH * 32) + h * 32;
        float acc = bv;
        #pragma unroll
        for (int d = 0; d < 32; ++d) acc = __builtin_fmaf(krow[d], w1c[d], acc);
        tile[kr][lane] = __expf(acc + acc);
    }
    __syncthreads();
    {
        int e4 = tid >> 4, k16 = tid & 15;
        float4 o;
        o.x = tile[k16][e4 * 4 + 0];
        o.y = tile[k16][e4 * 4 + 1];
        o.z = tile[k16][e4 * 4 + 2];
        o.w = tile[k16][e4 * 4 + 3];
        ((float4*)ws)[((size_t)(bh * 16 + e4)) * LK + k0 + k16] = o;
    }
}

// ---------------- Kernel 2: 6-wave, one k per lane, 8 q-rows per lane (v8f) ----------------
// grid = 768: bh = blk/48, q-tile of 8. Wave w owns k = w*64+lane. Zero intra-block
// Ek/V redundancy: 98 KB Ek + 48 KB V unique per block (was 196+96 with 2x redundancy).
__global__ __launch_bounds__(384) void attn_kernel(
    const float* __restrict__ qin, const float* __restrict__ vin,
    const int* __restrict__ qlens, const int* __restrict__ klens,
    const float* __restrict__ w1, const float* __restrict__ w2g,
    const float* __restrict__ ws,
    float* __restrict__ outg, float* __restrict__ attg)
{
    __shared__ __align__(32) float eqi_s[8 * 64];     // [e*8 + r] interleaved Eq
    __shared__ __align__(16) float att_h[6][512];     // [wave][r*64 + lane] wave-private e_
    __shared__ __align__(16) float w2s[64];
    __shared__ float2 smu[6][8];                      // [wave][row] (max, sum) partials
    __shared__ __align__(16) float4 pvp[6][8][8];     // [wave][row][dvq] scaled PV partials

    const int tid = threadIdx.x, wave = tid >> 6, lane = tid & 63;
    const int bh = blockIdx.x / 48, tile = blockIdx.x % 48;
    const int b = bh >> 3, h = bh & 7;
    const int q0 = tile * 8;
    const int klen = klens[b], qlen = qlens[b];

    // ---- Eq: waves 0..3 compute rows 2w, 2w+1 (e = lane); wave 4 stages w2 ----
    if (wave < 4) {
        float w1c[32];
        const float* w1p = w1 + (size_t)h * 64 * 64 + lane;
        #pragma unroll
        for (int d = 0; d < 32; ++d) w1c[d] = w1p[d * 64];
        #pragma unroll
        for (int j = 0; j < 2; ++j) {
            int r = wave * 2 + j;
            const float* qp = qin + ((size_t)(b * LQ + q0 + r)) * (NH * 32) + h * 32;
            float a = 0.f;
            #pragma unroll
            for (int d = 0; d < 32; ++d) a = __builtin_fmaf(qp[d], w1c[d], a);
            eqi_s[lane * 8 + r] = __expf(a + a);
        }
    } else if (wave == 4) {
        w2s[lane] = w2g[h * 64 + lane];
    }
    __syncthreads();   // (1)

    // ---- score: each lane owns k = wave*64 + lane, 8 q-rows; depth-2 prefetch ----
    v8f sc = sp8(0.f);
    const float4* ekp = (const float4*)ws + ((size_t)bh * 16) * LK + wave * 64 + lane;
    const v8f* eqv = (const v8f*)eqi_s;
    const float4* w2p = (const float4*)w2s;

    float4 kva = ekp[0];
    float4 kvb = ekp[LK];
    #pragma unroll
    for (int e4 = 0; e4 < 16; ++e4) {
        float4 kq = (e4 & 1) ? kvb : kva;
        if (e4 < 14) {
            float4 nx = ekp[(size_t)(e4 + 2) * LK];
            if (e4 & 1) kvb = nx; else kva = nx;
        }
        v8f E0 = eqv[e4 * 4 + 0];
        v8f E1 = eqv[e4 * 4 + 1];
        v8f E2 = eqv[e4 * 4 + 2];
        v8f E3 = eqv[e4 * 4 + 3];
        float4 wv = w2p[e4];
        v8f t0 = fma8(E0, sp8(kq.x), sp8(1.f));
        v8f t1 = fma8(E1, sp8(kq.y), sp8(1.f));
        v8f t2 = fma8(E2, sp8(kq.z), sp8(1.f));
        v8f t3 = fma8(E3, sp8(kq.w), sp8(1.f));
        v8f p12 = t0 * t1, p34 = t2 * t3;
        v8f n12 = fma8(sp8(wv.y), t0, sp8(wv.x) * t1);
        v8f n34 = fma8(sp8(wv.w), t2, sp8(wv.z) * t3);
        v8f num = fma8(n34, p12, n12 * p34);
        v8f den = p12 * p34;
        v8f rr;
        #pragma unroll
        for (int j = 0; j < 8; ++j) rr[j] = __builtin_amdgcn_rcpf(den[j]);
        sc = fma8(num, rr, sc);
    }

    // ---- wave-local softmax stats (8 rows, 64 k per wave) ----
    const int kk = wave * 64 + lane;
    const bool ok = kk < klen;
    float s_[8], m_[8];
    #pragma unroll
    for (int r = 0; r < 8; ++r) {
        s_[r] = ok ? -2.0f * sc[r] : -3.4e38f;
        m_[r] = s_[r];
    }
    #pragma unroll
    for (int off = 32; off >= 1; off >>= 1)
        #pragma unroll
        for (int r = 0; r < 8; ++r) m_[r] = fmaxf(m_[r], __shfl_xor(m_[r], off));
    float e_[8], u_[8];
    #pragma unroll
    for (int r = 0; r < 8; ++r) {
        e_[r] = ok ? __expf(s_[r] - m_[r]) : 0.f;
        u_[r] = e_[r];
    }
    #pragma unroll
    for (int off = 32; off >= 1; off >>= 1)
        #pragma unroll
        for (int r = 0; r < 8; ++r) u_[r] += __shfl_xor(u_[r], off);
    if (lane == 0) {
        #pragma unroll
        for (int r = 0; r < 8; ++r) smu[wave][r] = make_float2(m_[r], u_[r]);
    }
    // e_ -> wave-private LDS (same-wave RAW, no barrier)
    {
        float* ar = att_h[wave];
        #pragma unroll
        for (int r = 0; r < 8; ++r) ar[r * 64 + lane] = e_[r];
    }

    // ---- PV with UNNORMALIZED e_ weights over this wave's 64 k ----
    const int kf = lane >> 3, dg = lane & 7;
    const float* vbase = vin + (size_t)b * LK * (NH * 32) + h * 32
                       + (size_t)(wave * 64 + kf) * (NH * 32) + dg * 4;
    const float* ap = att_h[wave];
    float oa[8][4] = {{0.f,0.f,0.f,0.f},{0.f,0.f,0.f,0.f},{0.f,0.f,0.f,0.f},{0.f,0.f,0.f,0.f},
                      {0.f,0.f,0.f,0.f},{0.f,0.f,0.f,0.f},{0.f,0.f,0.f,0.f},{0.f,0.f,0.f,0.f}};
    float4 vbuf0 = *(const float4*)(vbase);
    float4 vbuf1 = *(const float4*)(vbase + (size_t)8 * (NH * 32));
    #pragma unroll
    for (int i = 0; i < 8; ++i) {
        float4 vv = (i & 1) ? vbuf1 : vbuf0;
        if (i < 6) {
            float4 nx = *(const float4*)(vbase + (size_t)((i + 2) * 8) * (NH * 32));
            if (i & 1) vbuf1 = nx; else vbuf0 = nx;
        }
        int k0 = i * 8;
        #pragma unroll
        for (int r = 0; r < 8; ++r) {
            float a = ap[r * 64 + k0 + kf];
            oa[r][0] = __builtin_fmaf(a, vv.x, oa[r][0]);
            oa[r][1] = __builtin_fmaf(a, vv.y, oa[r][1]);
            oa[r][2] = __builtin_fmaf(a, vv.z, oa[r][2]);
            oa[r][3] = __builtin_fmaf(a, vv.w, oa[r][3]);
        }
    }
    #pragma unroll
    for (int r = 0; r < 8; ++r)
        #pragma unroll
        for (int u = 0; u < 4; ++u) {
            oa[r][u] += __shfl_xor(oa[r][u], 8);
            oa[r][u] += __shfl_xor(oa[r][u], 16);
            oa[r][u] += __shfl_xor(oa[r][u], 32);
        }
    __syncthreads();   // (2) smu written by all waves pre-PV; near-free sync

    // ---- normalization factors: 6-way cross-wave merge, per row ----
    float f_[8];
    #pragma unroll
    for (int r = 0; r < 8; ++r) {
        float2 p0 = smu[0][r], p1 = smu[1][r], p2 = smu[2][r];
        float2 p3 = smu[3][r], p4 = smu[4][r], p5 = smu[5][r];
        float mm = fmaxf(fmaxf(fmaxf(p0.x, p1.x), fmaxf(p2.x, p3.x)), fmaxf(p4.x, p5.x));
        float uu = p0.y * __expf(p0.x - mm) + p1.y * __expf(p1.x - mm)
                 + p2.y * __expf(p2.x - mm) + p3.y * __expf(p3.x - mm)
                 + p4.y * __expf(p4.x - mm) + p5.y * __expf(p5.x - mm);
        f_[r] = __expf(m_[r] - mm) * __builtin_amdgcn_rcpf(uu);
    }

    if (kf == 0) {   // lanes 0..7: scale reduced partials by this wave's factor
        #pragma unroll
        for (int r = 0; r < 8; ++r)
            pvp[wave][r][dg] = make_float4(oa[r][0] * f_[r], oa[r][1] * f_[r],
                                           oa[r][2] * f_[r], oa[r][3] * f_[r]);
    }

    // ---- att global writes: p = e_ * f (coalesced, this wave's k-range) ----
    {
        float* ag = attg + ((size_t)(bh * LQ + q0)) * LK + wave * 64 + lane;
        #pragma unroll
        for (int r = 0; r < 8; ++r) ag[(size_t)r * LK] = e_[r] * f_[r];
    }
    __syncthreads();   // (3)

    // ---- combine PV partials: wave 0, lane = r*8 + dg ----
    if (wave == 0) {
        int r = lane >> 3, dgo = lane & 7;
        float4 x0 = pvp[0][r][dgo], x1 = pvp[1][r][dgo], x2 = pvp[2][r][dgo];
        float4 x3 = pvp[3][r][dgo], x4 = pvp[4][r][dgo], x5 = pvp[5][r][dgo];
        int q = q0 + r;
        bool okq = (q < qlen);
        float4 o4;
        o4.x = okq ? (x0.x + x1.x + x2.x + x3.x + x4.x + x5.x) : 0.f;
        o4.y = okq ? (x0.y + x1.y + x2.y + x3.y + x4.y + x5.y) : 0.f;
        o4.z = okq ? (x0.z + x1.z + x2.z + x3.z + x4.z + x5.z) : 0.f;
        o4.w = okq ? (x0.w + x1.w + x2.w + x3.w + x4.w + x5.w) : 0.f;
        ((float4*)(outg + ((size_t)(b * LQ + q)) * (NH * 32) + h * 32))[dgo] = o4;
    }
}

extern "C" void kernel_launch(void* const* d_in, const int* in_sizes, int n_in,
                              void* d_out, int out_size, void* d_ws, size_t ws_size,
                              hipStream_t stream) {
    const float* q    = (const float*)d_in[0];
    const float* k    = (const float*)d_in[1];
    const float* v    = (const float*)d_in[2];
    const int*   qlen = (const int*)d_in[3];
    const int*   klen = (const int*)d_in[4];
    const float* w1   = (const float*)d_in[5];
    const float* b1   = (const float*)d_in[6];
    const float* w2   = (const float*)d_in[7];
    float* out = (float*)d_out;
    float* att = out + (size_t)BS * LQ * NH * 32;   // out: 196608, att: 2359296 floats
    float* ws  = (float*)d_ws;                      // Ek [bh][e4][k][4]: 1.5 MB

    pre_ek_kernel<<<384, 256, 0, stream>>>(k, w1, b1, ws);
    attn_kernel<<<768, 384, 0, stream>>>(q, v, qlen, klen, w1, w2, ws, out, att);
}

// Round 3
// 93.736 us; speedup vs baseline: 1.1247x; 1.1247x over previous
//
#include <hip/hip_runtime.h>

#define NH 8
#define LQ 384
#define LK 384
#define BS 2

typedef float v4f __attribute__((ext_vector_type(4)));
__device__ __forceinline__ v4f fma4(v4f a, v4f b, v4f c) { return __builtin_elementwise_fma(a, b, c); }
__device__ __forceinline__ v4f sp4(float x) { v4f r; r.x = x; r.y = x; r.z = x; r.w = x; return r; }

// ---------------- Kernel 1: Ek = exp(2*(kW+b1)), layout [bh][e4][k][4] ----------------
// grid = 384: bh = bid/24, 16-k tile. 1.5 blocks/CU.
__global__ __launch_bounds__(256) void pre_ek_kernel(
    const float* __restrict__ kin, const float* __restrict__ w1,
    const float* __restrict__ b1, float* __restrict__ ws)
{
    __shared__ float tile[16][65];
    const int bid = blockIdx.x;
    const int bh = bid / 24, kt = bid % 24;
    const int b = bh >> 3, h = bh & 7;
    const int k0 = kt * 16;
    const int tid = threadIdx.x;
    const int lane = tid & 63, w = tid >> 6;

    float w1c[32];
    const float* w1p = w1 + (size_t)(h * 64 + 32) * 64 + lane;
    #pragma unroll
    for (int d = 0; d < 32; ++d) w1c[d] = w1p[d * 64];
    const float bv = b1[h * 64 + lane];

    #pragma unroll
    for (int s = 0; s < 4; ++s) {
        int kr = w * 4 + s;
        const float* krow = kin + ((size_t)(b * LK + k0 + kr)) * (NH * 32) + h * 32;
        float acc = bv;
        #pragma unroll
        for (int d = 0; d < 32; ++d) acc = __builtin_fmaf(krow[d], w1c[d], acc);
        tile[kr][lane] = __expf(acc + acc);
    }
    __syncthreads();
    {
        int e4 = tid >> 4, k16 = tid & 15;
        float4 o;
        o.x = tile[k16][e4 * 4 + 0];
        o.y = tile[k16][e4 * 4 + 1];
        o.z = tile[k16][e4 * 4 + 2];
        o.w = tile[k16][e4 * 4 + 3];
        ((float4*)ws)[((size_t)(bh * 16 + e4)) * LK + k0 + k16] = o;
    }
}

// ---------------- Kernel 2: quad-row (v4f) score + paired-rcp + deferred-normalization PV ----------------
// grid = 768 (3 blocks/CU): bh = blk/48, q-tile of 8; wave=(pair4, k-half), 4 q-rows per lane.
// Score inner loop merges rcp across e4-quad PAIRS: 8 e-terms share one v_rcp per row (-23% score cyc).
__global__ __launch_bounds__(256) void attn_kernel(
    const float* __restrict__ qin, const float* __restrict__ vin,
    const int* __restrict__ qlens, const int* __restrict__ klens,
    const float* __restrict__ w1, const float* __restrict__ w2g,
    const float* __restrict__ ws,
    float* __restrict__ outg, float* __restrict__ attg)
{
    __shared__ __align__(16) float eqi_s[2][256];      // [pair4][e*4+row] interleaved Eq
    __shared__ __align__(16) float att_h[4][4 * 192];  // [wave][row*192 + k] wave-private e_
    __shared__ __align__(16) float w2s[64];
    __shared__ float2 smu[2][4][2];                    // [pair4][row][half] (max, sum)
    __shared__ __align__(16) float4 pvp[2][2][4][8];   // [pair4][half][row][dvq]

    const int tid = threadIdx.x, wave = tid >> 6, lane = tid & 63;
    const int pair = wave >> 1, hh = wave & 1;
    const int bh = blockIdx.x / 48, tile = blockIdx.x % 48;
    const int b = bh >> 3, h = bh & 7;
    const int q0 = tile * 8;
    const int klen = klens[b], qlen = qlens[b];

    // ---- Eq: wave w computes rows 2w, 2w+1 (e = lane), interleaved 4-row groups ----
    {
        float w1c[32];
        const float* w1p = w1 + (size_t)h * 64 * 64 + lane;
        #pragma unroll
        for (int d = 0; d < 32; ++d) w1c[d] = w1p[d * 64];
        #pragma unroll
        for (int j = 0; j < 2; ++j) {
            int r = wave * 2 + j;
            const float* qp = qin + ((size_t)(b * LQ + q0 + r)) * (NH * 32) + h * 32;
            float a = 0.f;
            #pragma unroll
            for (int d = 0; d < 32; ++d) a = __builtin_fmaf(qp[d], w1c[d], a);
            eqi_s[r >> 2][lane * 4 + (r & 3)] = __expf(a + a);
        }
        if (wave == 0) w2s[lane] = w2g[h * 64 + lane];
    }
    __syncthreads();   // (1)

    // ---- score: k = hh*192 + c*64 + lane; 4 q-rows per lane; e4 pairs share one rcp ----
    v4f sc[3];
    sc[0] = sp4(0.f); sc[1] = sp4(0.f); sc[2] = sp4(0.f);
    const float4* ekq = (const float4*)ws + ((size_t)bh * 16) * LK + hh * 192 + lane;
    const v4f*   eqp = (const v4f*)eqi_s[pair];
    const float4* w2p = (const float4*)w2s;

    float4 kva[3], kvb[3];
    #pragma unroll
    for (int c = 0; c < 3; ++c) kva[c] = ekq[c * 64];
    #pragma unroll
    for (int c = 0; c < 3; ++c) kvb[c] = ekq[LK + c * 64];

    #pragma unroll
    for (int p = 0; p < 8; ++p) {
        const int ea = 2 * p, eb = 2 * p + 1;
        float4 As[3] = {kva[0], kva[1], kva[2]};
        float4 Bs[3] = {kvb[0], kvb[1], kvb[2]};
        if (p < 7) {
            const float4* np = ekq + (size_t)(ea + 2) * LK;
            kva[0] = np[0]; kva[1] = np[64]; kva[2] = np[128];
            const float4* nq = ekq + (size_t)(eb + 2) * LK;
            kvb[0] = nq[0]; kvb[1] = nq[64]; kvb[2] = nq[128];
        }
        v4f Ea0 = eqp[ea * 4 + 0];
        v4f Ea1 = eqp[ea * 4 + 1];
        v4f Ea2 = eqp[ea * 4 + 2];
        v4f Ea3 = eqp[ea * 4 + 3];
        v4f Eb0 = eqp[eb * 4 + 0];
        v4f Eb1 = eqp[eb * 4 + 1];
        v4f Eb2 = eqp[eb * 4 + 2];
        v4f Eb3 = eqp[eb * 4 + 3];
        float4 wva = w2p[ea], wvb = w2p[eb];
        #pragma unroll
        for (int c = 0; c < 3; ++c) {
            float4 ka = As[c], kb = Bs[c];
            // quad A (e = 4*ea .. 4*ea+3)
            v4f ta0 = fma4(Ea0, sp4(ka.x), sp4(1.f));
            v4f ta1 = fma4(Ea1, sp4(ka.y), sp4(1.f));
            v4f ta2 = fma4(Ea2, sp4(ka.z), sp4(1.f));
            v4f ta3 = fma4(Ea3, sp4(ka.w), sp4(1.f));
            v4f pa12 = ta0 * ta1, pa34 = ta2 * ta3;
            v4f na12 = fma4(sp4(wva.y), ta0, sp4(wva.x) * ta1);
            v4f na34 = fma4(sp4(wva.w), ta2, sp4(wva.z) * ta3);
            v4f numA = fma4(na34, pa12, na12 * pa34);
            v4f denA = pa12 * pa34;
            // quad B (e = 4*eb .. 4*eb+3)
            v4f tb0 = fma4(Eb0, sp4(kb.x), sp4(1.f));
            v4f tb1 = fma4(Eb1, sp4(kb.y), sp4(1.f));
            v4f tb2 = fma4(Eb2, sp4(kb.z), sp4(1.f));
            v4f tb3 = fma4(Eb3, sp4(kb.w), sp4(1.f));
            v4f pb12 = tb0 * tb1, pb34 = tb2 * tb3;
            v4f nb12 = fma4(sp4(wvb.y), tb0, sp4(wvb.x) * tb1);
            v4f nb34 = fma4(sp4(wvb.w), tb2, sp4(wvb.z) * tb3);
            v4f numB = fma4(nb34, pb12, nb12 * pb34);
            v4f denB = pb12 * pb34;
            // merge: numA/denA + numB/denB = (numA*denB + numB*denA) / (denA*denB)
            v4f num = fma4(numB, denA, numA * denB);
            v4f den = denA * denB;
            v4f r;
            r.x = __builtin_amdgcn_rcpf(den.x);
            r.y = __builtin_amdgcn_rcpf(den.y);
            r.z = __builtin_amdgcn_rcpf(den.z);
            r.w = __builtin_amdgcn_rcpf(den.w);
            sc[c] = fma4(num, r, sc[c]);
        }
    }

    // ---- wave-local softmax stats (4 rows) ----
    float s_[3][4];
    float m_[4] = {-3.4e38f, -3.4e38f, -3.4e38f, -3.4e38f};
    #pragma unroll
    for (int c = 0; c < 3; ++c) {
        int kk = hh * 192 + c * 64 + lane;
        bool ok = kk < klen;
        #pragma unroll
        for (int r = 0; r < 4; ++r) {
            s_[c][r] = ok ? -2.0f * sc[c][r] : -3.4e38f;
            m_[r] = fmaxf(m_[r], s_[c][r]);
        }
    }
    #pragma unroll
    for (int off = 32; off >= 1; off >>= 1) {
        #pragma unroll
        for (int r = 0; r < 4; ++r) m_[r] = fmaxf(m_[r], __shfl_xor(m_[r], off));
    }
    float e_[3][4];
    float u_[4] = {0.f, 0.f, 0.f, 0.f};
    #pragma unroll
    for (int c = 0; c < 3; ++c) {
        int kk = hh * 192 + c * 64 + lane;
        bool ok = kk < klen;
        #pragma unroll
        for (int r = 0; r < 4; ++r) {
            e_[c][r] = ok ? __expf(s_[c][r] - m_[r]) : 0.f;
            u_[r] += e_[c][r];
        }
    }
    #pragma unroll
    for (int off = 32; off >= 1; off >>= 1) {
        #pragma unroll
        for (int r = 0; r < 4; ++r) u_[r] += __shfl_xor(u_[r], off);
    }
    if (lane == 0) {
        #pragma unroll
        for (int r = 0; r < 4; ++r) smu[pair][r][hh] = make_float2(m_[r], u_[r]);
    }
    // e_ -> wave-private LDS (same-wave RAW, no barrier)
    {
        float* ar = att_h[wave];
        #pragma unroll
        for (int c = 0; c < 3; ++c)
            #pragma unroll
            for (int r = 0; r < 4; ++r)
                ar[r * 192 + c * 64 + lane] = e_[c][r];
    }

    // ---- PV with UNNORMALIZED e_ weights (normalization deferred past the exchange) ----
    const int kf = lane >> 3, dg = lane & 7;
    const float* vbase = vin + (size_t)b * LK * (NH * 32) + h * 32
                       + (size_t)(hh * 192 + kf) * (NH * 32) + dg * 4;
    const float* ap = att_h[wave];
    float oa[4][4] = {{0.f,0.f,0.f,0.f},{0.f,0.f,0.f,0.f},{0.f,0.f,0.f,0.f},{0.f,0.f,0.f,0.f}};
    float4 vbuf[2];
    vbuf[0] = *(const float4*)(vbase);
    vbuf[1] = *(const float4*)(vbase + (size_t)8 * (NH * 32));
    #pragma unroll
    for (int i = 0; i < 24; ++i) {
        float4 vv = vbuf[i & 1];
        if (i < 22) vbuf[i & 1] = *(const float4*)(vbase + (size_t)((i + 2) * 8) * (NH * 32));
        int k0 = i * 8;
        #pragma unroll
        for (int r = 0; r < 4; ++r) {
            float a = ap[r * 192 + k0 + kf];
            oa[r][0] = __builtin_fmaf(a, vv.x, oa[r][0]);
            oa[r][1] = __builtin_fmaf(a, vv.y, oa[r][1]);
            oa[r][2] = __builtin_fmaf(a, vv.z, oa[r][2]);
            oa[r][3] = __builtin_fmaf(a, vv.w, oa[r][3]);
        }
    }
    #pragma unroll
    for (int r = 0; r < 4; ++r)
        #pragma unroll
        for (int u = 0; u < 4; ++u) {
            oa[r][u] += __shfl_xor(oa[r][u], 8);
            oa[r][u] += __shfl_xor(oa[r][u], 16);
            oa[r][u] += __shfl_xor(oa[r][u], 32);
        }
    __syncthreads();   // (2) smu written long ago by all waves; near-free sync

    // ---- normalization factors (cross-half merge), per row ----
    float f_[4];
    #pragma unroll
    for (int r = 0; r < 4; ++r) {
        float2 A = smu[pair][r][0], B = smu[pair][r][1];
        float mm = fmaxf(A.x, B.x);
        float uu = A.y * __expf(A.x - mm) + B.y * __expf(B.x - mm);
        f_[r] = __expf(m_[r] - mm) * __builtin_amdgcn_rcpf(uu);
    }

    if (kf == 0) {   // lanes 0..7: scale reduced partials by this half's factor
        #pragma unroll
        for (int r = 0; r < 4; ++r)
            pvp[pair][hh][r][dg] = make_float4(oa[r][0] * f_[r], oa[r][1] * f_[r],
                                               oa[r][2] * f_[r], oa[r][3] * f_[r]);
    }
    __syncthreads();   // (3)

    // ---- combine PV halves: wave w -> rows 2w, 2w+1; lanes 0..15 ----
    if (lane < 16) {
        int r = wave * 2 + (lane >> 3);
        int dgo = lane & 7;
        int q = q0 + r;
        float4 xa = pvp[r >> 2][0][r & 3][dgo];
        float4 xb = pvp[r >> 2][1][r & 3][dgo];
        float4 o4;
        bool ok = (q < qlen);
        o4.x = ok ? (xa.x + xb.x) : 0.f;
        o4.y = ok ? (xa.y + xb.y) : 0.f;
        o4.z = ok ? (xa.z + xb.z) : 0.f;
        o4.w = ok ? (xa.w + xb.w) : 0.f;
        ((float4*)(outg + ((size_t)(b * LQ + q)) * (NH * 32) + h * 32))[dgo] = o4;
    }

    // ---- att global writes: p = e_ * f (coalesced, from regs) ----
    {
        float* ag = attg + ((size_t)(bh * LQ + q0 + pair * 4)) * LK + hh * 192;
        #pragma unroll
        for (int r = 0; r < 4; ++r) {
            #pragma unroll
            for (int c = 0; c < 3; ++c) ag[c * 64 + lane] = e_[c][r] * f_[r];
            ag += LK;
        }
    }
}

extern "C" void kernel_launch(void* const* d_in, const int* in_sizes, int n_in,
                              void* d_out, int out_size, void* d_ws, size_t ws_size,
                              hipStream_t stream) {
    const float* q    = (const float*)d_in[0];
    const float* k    = (const float*)d_in[1];
    const float* v    = (const float*)d_in[2];
    const int*   qlen = (const int*)d_in[3];
    const int*   klen = (const int*)d_in[4];
    const float* w1   = (const float*)d_in[5];
    const float* b1   = (const float*)d_in[6];
    const float* w2   = (const float*)d_in[7];
    float* out = (float*)d_out;
    float* att = out + (size_t)BS * LQ * NH * 32;   // out: 196608, att: 2359296 floats
    float* ws  = (float*)d_ws;                      // Ek [bh][e4][k][4]: 1.5 MB

    pre_ek_kernel<<<384, 256, 0, stream>>>(k, w1, b1, ws);
    attn_kernel<<<768, 256, 0, stream>>>(q, v, qlen, klen, w1, w2, ws, out, att);
}